// Round 2
// baseline (1772.319 us; speedup 1.0000x reference)
//
#include <hip/hip_runtime.h>
#include <hip/hip_bf16.h>
#include <cstdint>
#include <cstddef>

// Problem constants
//   B=2 S=4096 DM=3584 H=112 DH=64 INNER=7168 CHUNK=256
//   GEMM1: [8192 x 3584] * [14336 x 3584]^T -> xz [8192 x 14336] (bf16)
//   scan:  y[s] = A*y[s-256] + 0.1*x[s]; y *= sigmoid(z); in-place into x half
//   GEMM2: [8192 x 7168 (lda 14336)] * [3584 x 7168]^T -> out [8192 x 3584] f32
//
// GEMMs: 256x256 8-phase schedule (T2 swizzle + T3/T4 counted vmcnt + T5
// setprio + T1 XCD swizzle), 512 threads = 8 waves (2M x 4N), BK=64, 4 phases
// per K-tile, one half-tile staged per phase, vmcnt(6) at tile boundary only.
// This round: MFMA shape 16x16x32 -> 32x32x16 (µbench 2075 -> 2382+ TF,
// +15% matrix-pipe FLOP/cyc). LDS layout/staging/stagger unchanged.

typedef __bf16 bf16x8 __attribute__((ext_vector_type(8)));
typedef float f32x16 __attribute__((ext_vector_type(16)));
typedef unsigned short us8 __attribute__((ext_vector_type(8)));

__device__ __forceinline__ unsigned short f2bf(float f) {
  return __builtin_bit_cast(unsigned short, (__bf16)f);
}
__device__ __forceinline__ float bf2f(unsigned short u) {
  return (float)__builtin_bit_cast(__bf16, u);
}

// async global->LDS, 16B per lane; LDS dest is wave-uniform base + lane*16
__device__ __forceinline__ void async_lds16(const unsigned short* g, unsigned short* l) {
  __builtin_amdgcn_global_load_lds(
      (__attribute__((address_space(1))) void*)(size_t)(const void*)g,
      (__attribute__((address_space(3))) void*)l,
      16, 0, 0);
}

// ---------------- f32 -> bf16 cast (4 elems/thread) ----------------
__global__ __launch_bounds__(256) void cvt_f32_bf16(
    const float* __restrict__ src, unsigned short* __restrict__ dst, int n4) {
  int t = blockIdx.x * 256 + threadIdx.x;
  if (t >= n4) return;
  float4 v = reinterpret_cast<const float4*>(src)[t];
  ushort4 o;
  o.x = f2bf(v.x); o.y = f2bf(v.y); o.z = f2bf(v.z); o.w = f2bf(v.w);
  reinterpret_cast<ushort4*>(dst)[t] = o;
}

// ---------------- 256x256 8-phase bf16 GEMM, C = A * B^T ------------------
// A: [M x lda] bf16 (K contiguous), B: [N x ldb] bf16, C: [M x N] ld=ldc.
// LDS: 2 bufs x {A,B} x {K-half 0,1}, each half = 256 rows x 32 elems (16 KB)
// = 128 KiB total. Row r granule g (16B, 4/row) stored at slot g ^ ((r>>1)&3):
// any 16-lane group covers all 8 bank-quads 2-way (free, m136).
// Fragments: 32x32x16 MFMA; wave tile 128x64 = 4(M) x 2(N) frags, K-step 16.
// A-frag read: row = l&31, k-granule = (l>>5) + 2*ks -> 2-way conflict-free.
// Phase (mh,kh): reads A m-frags {mh*2,mh*2+1} x ks{0,1} (+B when mh==0),
// stage ONE half-tile, barrier, lgkmcnt(0), setprio(1), 8 MFMA, setprio(0),
// barrier. Stagger: (t,P0)->t+1 A-k1, (t,P1)->t+2 B-k0, (t,P2)->t+2 A-k0,
// (t,P3)->t+2 B-k1. Boundary vmcnt(6) = 3 half-tiles in flight.
template <bool OUT_BF16>
__global__ __launch_bounds__(512, 2) void gemm256(
    const unsigned short* __restrict__ A, const unsigned short* __restrict__ Bm,
    void* __restrict__ Cv, int K, int lda, int ldb, int ldc) {
  __shared__ __align__(16) unsigned short lds[65536];  // 128 KiB

  const int tid  = threadIdx.x;
  const int lane = tid & 63;
  const int wave = tid >> 6;

  // T1: XCD-aware bijective block swizzle (launcher guarantees nwg % 8 == 0)
  const int nbx  = gridDim.x;
  const int nwg  = nbx * gridDim.y;
  const int orig = blockIdx.y * nbx + blockIdx.x;
  const int swz  = (orig & 7) * (nwg >> 3) + (orig >> 3);
  const int bm   = (swz / nbx) * 256;
  const int bn   = (swz % nbx) * 256;

  const int wm  = wave >> 2;        // 0..1: 128-row block
  const int wn  = wave & 3;         // 0..3: 64-col block
  const int l31 = lane & 31;
  const int hi  = lane >> 5;        // k-granule half
  const int sw  = (l31 >> 1) & 3;   // read-side swizzle
  const int so0 = (hi ^ sw) * 8;          // elem offset, ks=0 granule
  const int so1 = ((hi ^ sw) ^ 2) * 8;    // elem offset, ks=1 granule
  const int aoff = (wm * 128 + l31) * 32; // wave's A row base within region
  const int boff = (wn * 64  + l31) * 32; // wave's B row base within region

  // staging geometry: granule idx = j*512 + wave*64 + lane
  //   row = (granule)>>2, slot = granule&3; global granule = slot ^ ((row>>1)&3)
  const int srow = wave * 16 + (lane >> 2);
  const int sg   = (lane & 3) ^ ((lane >> 3) & 3);   // pre-swizzled global granule
  const unsigned short* gAr = A  + (size_t)(bm + srow) * lda + sg * 8;
  const unsigned short* gBr = Bm + (size_t)(bn + srow) * ldb + sg * 8;

  auto STAGE = [&](int t, int mat, int kh) {
    unsigned short* ldst = lds + ((((t & 1) * 2 + mat) * 2 + kh) << 13) + wave * 512;
    const unsigned short* g = (mat ? gBr : gAr) + t * 64 + kh * 32;
    const size_t ldx = mat ? (size_t)ldb : (size_t)lda;
    async_lds16(g, ldst);                     // rows 0..127 of region
    async_lds16(g + 128 * ldx, ldst + 4096);  // rows 128..255
  };

  f32x16 acc[4][2];
#pragma unroll
  for (int i = 0; i < 4; ++i)
#pragma unroll
    for (int j = 0; j < 2; ++j)
#pragma unroll
      for (int r = 0; r < 16; ++r) acc[i][j][r] = 0.f;

  const int NT = K >> 6;

  // prologue: tile0 full + tile1 {B-k0, A-k0, B-k1}; newest 3 may stay in flight
  STAGE(0, 0, 0); STAGE(0, 1, 0); STAGE(0, 0, 1); STAGE(0, 1, 1);
  if (NT > 1) {
    STAGE(1, 1, 0); STAGE(1, 0, 0); STAGE(1, 1, 1);
    asm volatile("s_waitcnt vmcnt(6)" ::: "memory");
  } else {
    asm volatile("s_waitcnt vmcnt(0)" ::: "memory");
  }
  __builtin_amdgcn_s_barrier();

  for (int t = 0; t < NT; ++t) {
    const unsigned short* Ak0 = lds + (t & 1) * 32768;
    const unsigned short* Ak1 = Ak0 + 8192;
    const unsigned short* Bk0 = Ak0 + 16384;
    const unsigned short* Bk1 = Ak0 + 24576;

    bf16x8 a[2][2], b[2][2];   // [frag][ks]

    // ---- P0: mh=0, kh=0 ----
    a[0][0] = *reinterpret_cast<const bf16x8*>(Ak0 + aoff + so0);
    a[0][1] = *reinterpret_cast<const bf16x8*>(Ak0 + aoff + so1);
    a[1][0] = *reinterpret_cast<const bf16x8*>(Ak0 + aoff + 1024 + so0);
    a[1][1] = *reinterpret_cast<const bf16x8*>(Ak0 + aoff + 1024 + so1);
    b[0][0] = *reinterpret_cast<const bf16x8*>(Bk0 + boff + so0);
    b[0][1] = *reinterpret_cast<const bf16x8*>(Bk0 + boff + so1);
    b[1][0] = *reinterpret_cast<const bf16x8*>(Bk0 + boff + 1024 + so0);
    b[1][1] = *reinterpret_cast<const bf16x8*>(Bk0 + boff + 1024 + so1);
    if (t + 1 < NT) STAGE(t + 1, 0, 1);
    __builtin_amdgcn_s_barrier();
    asm volatile("s_waitcnt lgkmcnt(0)" ::: "memory");
    __builtin_amdgcn_s_setprio(1);
#pragma unroll
    for (int mf = 0; mf < 2; ++mf)
#pragma unroll
      for (int nf = 0; nf < 2; ++nf) {
        acc[mf][nf] = __builtin_amdgcn_mfma_f32_32x32x16_bf16(a[mf][0], b[nf][0], acc[mf][nf], 0, 0, 0);
        acc[mf][nf] = __builtin_amdgcn_mfma_f32_32x32x16_bf16(a[mf][1], b[nf][1], acc[mf][nf], 0, 0, 0);
      }
    __builtin_amdgcn_s_setprio(0);
    __builtin_amdgcn_s_barrier();

    // ---- P1: mh=1, kh=0 (B regs reused) ----
    a[0][0] = *reinterpret_cast<const bf16x8*>(Ak0 + aoff + 2048 + so0);
    a[0][1] = *reinterpret_cast<const bf16x8*>(Ak0 + aoff + 2048 + so1);
    a[1][0] = *reinterpret_cast<const bf16x8*>(Ak0 + aoff + 3072 + so0);
    a[1][1] = *reinterpret_cast<const bf16x8*>(Ak0 + aoff + 3072 + so1);
    if (t + 2 < NT) STAGE(t + 2, 1, 0);
    __builtin_amdgcn_s_barrier();
    asm volatile("s_waitcnt lgkmcnt(0)" ::: "memory");
    __builtin_amdgcn_s_setprio(1);
#pragma unroll
    for (int mf = 0; mf < 2; ++mf)
#pragma unroll
      for (int nf = 0; nf < 2; ++nf) {
        acc[2 + mf][nf] = __builtin_amdgcn_mfma_f32_32x32x16_bf16(a[mf][0], b[nf][0], acc[2 + mf][nf], 0, 0, 0);
        acc[2 + mf][nf] = __builtin_amdgcn_mfma_f32_32x32x16_bf16(a[mf][1], b[nf][1], acc[2 + mf][nf], 0, 0, 0);
      }
    __builtin_amdgcn_s_setprio(0);
    __builtin_amdgcn_s_barrier();

    // ---- P2: mh=0, kh=1 ----
    a[0][0] = *reinterpret_cast<const bf16x8*>(Ak1 + aoff + so0);
    a[0][1] = *reinterpret_cast<const bf16x8*>(Ak1 + aoff + so1);
    a[1][0] = *reinterpret_cast<const bf16x8*>(Ak1 + aoff + 1024 + so0);
    a[1][1] = *reinterpret_cast<const bf16x8*>(Ak1 + aoff + 1024 + so1);
    b[0][0] = *reinterpret_cast<const bf16x8*>(Bk1 + boff + so0);
    b[0][1] = *reinterpret_cast<const bf16x8*>(Bk1 + boff + so1);
    b[1][0] = *reinterpret_cast<const bf16x8*>(Bk1 + boff + 1024 + so0);
    b[1][1] = *reinterpret_cast<const bf16x8*>(Bk1 + boff + 1024 + so1);
    if (t + 2 < NT) STAGE(t + 2, 0, 0);
    __builtin_amdgcn_s_barrier();
    asm volatile("s_waitcnt lgkmcnt(0)" ::: "memory");
    __builtin_amdgcn_s_setprio(1);
#pragma unroll
    for (int mf = 0; mf < 2; ++mf)
#pragma unroll
      for (int nf = 0; nf < 2; ++nf) {
        acc[mf][nf] = __builtin_amdgcn_mfma_f32_32x32x16_bf16(a[mf][0], b[nf][0], acc[mf][nf], 0, 0, 0);
        acc[mf][nf] = __builtin_amdgcn_mfma_f32_32x32x16_bf16(a[mf][1], b[nf][1], acc[mf][nf], 0, 0, 0);
      }
    __builtin_amdgcn_s_setprio(0);
    __builtin_amdgcn_s_barrier();

    // ---- P3: mh=1, kh=1 (B regs reused) ----
    a[0][0] = *reinterpret_cast<const bf16x8*>(Ak1 + aoff + 2048 + so0);
    a[0][1] = *reinterpret_cast<const bf16x8*>(Ak1 + aoff + 2048 + so1);
    a[1][0] = *reinterpret_cast<const bf16x8*>(Ak1 + aoff + 3072 + so0);
    a[1][1] = *reinterpret_cast<const bf16x8*>(Ak1 + aoff + 3072 + so1);
    if (t + 2 < NT) STAGE(t + 2, 1, 1);
    __builtin_amdgcn_s_barrier();
    asm volatile("s_waitcnt lgkmcnt(0)" ::: "memory");
    __builtin_amdgcn_s_setprio(1);
#pragma unroll
    for (int mf = 0; mf < 2; ++mf)
#pragma unroll
      for (int nf = 0; nf < 2; ++nf) {
        acc[2 + mf][nf] = __builtin_amdgcn_mfma_f32_32x32x16_bf16(a[mf][0], b[nf][0], acc[2 + mf][nf], 0, 0, 0);
        acc[2 + mf][nf] = __builtin_amdgcn_mfma_f32_32x32x16_bf16(a[mf][1], b[nf][1], acc[2 + mf][nf], 0, 0, 0);
      }
    __builtin_amdgcn_s_setprio(0);
    // tile-boundary counted drain: next tile fully landed, 3 half-tiles in flight
    if (t == NT - 2)      asm volatile("s_waitcnt vmcnt(0)" ::: "memory");
    else if (t < NT - 2)  asm volatile("s_waitcnt vmcnt(6)" ::: "memory");
    __builtin_amdgcn_s_barrier();
  }

  // epilogue: 32x32 C/D layout col=lane&31, row=(reg&3)+8*(reg>>2)+4*(lane>>5)
#pragma unroll
  for (int mf = 0; mf < 4; ++mf) {
#pragma unroll
    for (int nf = 0; nf < 2; ++nf) {
      const int col = bn + wn * 64 + nf * 32 + l31;
      const int rbase = bm + wm * 128 + mf * 32 + 4 * hi;
#pragma unroll
      for (int r = 0; r < 16; ++r) {
        const int row = rbase + (r & 3) + 8 * (r >> 2);
        if (OUT_BF16)
          ((unsigned short*)Cv)[(size_t)row * ldc + col] = f2bf(acc[mf][nf][r]);
        else
          ((float*)Cv)[(size_t)row * ldc + col] = acc[mf][nf][r];
      }
    }
  }
}

// ---------------- chunked decay scan + sigmoid gate (in-place on x half) ----
__global__ __launch_bounds__(256) void scan_gate(
    unsigned short* __restrict__ xz, const float* __restrict__ A_log) {
  const int tid = blockIdx.x * 256 + threadIdx.x;   // 458752 total
  const int i8 = tid % 896;
  const int rb = tid / 896;
  const int r = rb & 255;
  const int b = rb >> 8;
  const int i = i8 * 8;
  const float Ah = __expf(-fabsf(A_log[i >> 6]));   // head = i/64

  float st[8];
#pragma unroll
  for (int j = 0; j < 8; ++j) st[j] = 0.f;

  const size_t base = ((size_t)b * 4096 + r) * 14336 + i;
#pragma unroll
  for (int c = 0; c < 16; ++c) {
    const size_t off = base + (size_t)c * (256 * 14336);
    us8 xr = *reinterpret_cast<const us8*>(xz + off);
    us8 zr = *reinterpret_cast<const us8*>(xz + off + 7168);
    us8 yo;
#pragma unroll
    for (int j = 0; j < 8; ++j) {
      st[j] = st[j] * Ah + 0.1f * bf2f(xr[j]);
      const float zv = bf2f(zr[j]);
      const float sg = 1.f / (1.f + __expf(-zv));
      yo[j] = f2bf(st[j] * sg);
    }
    *reinterpret_cast<us8*>(xz + off) = yo;  // y overwrites x slot
  }
}

extern "C" void kernel_launch(void* const* d_in, const int* in_sizes, int n_in,
                              void* d_out, int out_size, void* d_ws, size_t ws_size,
                              hipStream_t stream) {
  const float* hidden = (const float*)d_in[0];   // [2,4096,3584]
  const float* W_in   = (const float*)d_in[1];   // [14336,3584]
  const float* W_out  = (const float*)d_in[2];   // [3584,7168]
  const float* A_log  = (const float*)d_in[3];   // [112]

  // workspace layout (bf16 elems): hid | win | wout | xz   = 447.7 MB total
  unsigned short* hid_bf  = (unsigned short*)d_ws;
  unsigned short* win_bf  = hid_bf  + 29360128ull;   // 2*4096*3584
  unsigned short* wout_bf = win_bf  + 51380224ull;   // 14336*3584
  unsigned short* xz      = wout_bf + 25690112ull;   // 3584*7168; xz = 8192*14336

  cvt_f32_bf16<<<29360128 / 4 / 256, 256, 0, stream>>>(hidden, hid_bf, 29360128 / 4);
  cvt_f32_bf16<<<51380224 / 4 / 256, 256, 0, stream>>>(W_in, win_bf, 51380224 / 4);
  cvt_f32_bf16<<<25690112 / 4 / 256, 256, 0, stream>>>(W_out, wout_bf, 25690112 / 4);

  // GEMM1: xz = hidden * W_in^T   (M=8192, N=14336, K=3584) -> 56x32 = 1792 wgs
  gemm256<true><<<dim3(14336 / 256, 8192 / 256), 512, 0, stream>>>(
      hid_bf, win_bf, xz, 3584, 3584, 3584, 14336);

  scan_gate<<<1792, 256, 0, stream>>>(xz, A_log);

  // GEMM2: out = y * W_out^T   (M=8192, N=3584, K=7168, A lda=14336) -> 14x32 = 448 wgs
  gemm256<false><<<dim3(3584 / 256, 8192 / 256), 512, 0, stream>>>(
      xz, wout_bf, d_out, 7168, 14336, 7168, 3584);
}

// Round 3
// 1601.427 us; speedup vs baseline: 1.1067x; 1.1067x over previous
//
#include <hip/hip_runtime.h>
#include <hip/hip_bf16.h>
#include <cstdint>
#include <cstddef>

// Problem constants
//   B=2 S=4096 DM=3584 H=112 DH=64 INNER=7168 CHUNK=256
//   GEMM1: [8192 x 3584] * [14336 x 3584]^T -> xz [8192 x 14336] (bf16)
//   scan:  y[s] = A*y[s-256] + 0.1*x[s]; y *= sigmoid(z); in-place into x half
//   GEMM2: [8192 x 7168 (lda 14336)] * [3584 x 7168]^T -> out [8192 x 3584] f32
//
// GEMM: 256x256 tile, 8 waves (2M x 4N), BK=64, 16x16x32 MFMA (reverted from
// 32x32x16: that layout measured 7.7e7 bank conflicts, 0 here).
// This round: one-phase-ahead register pipelining + 4 barriers/tile (was 8).
// Hazard ledger (regions of current buffer, staged-into by t+2 stages):
//   B.k0 read P0 (drained pre-P0-MFMA)  -> staged in P1 after barrier#1  OK
//   A.k0 read P0+P1 (drained pre-MFMA)  -> staged in P2 after barrier#2  OK
//   B.k1 read P2 (drained pre-P2-MFMA)  -> staged in P3 after barrier#3  OK
//   A.k1 (other buf) read t-1 P1/P2     -> staged in P0 after boundary   OK
// Boundary vmcnt(6) = 3 newest half-tile stages in flight (t+2's P1-P3).

typedef __bf16 bf16x8 __attribute__((ext_vector_type(8)));
typedef float f32x4 __attribute__((ext_vector_type(4)));
typedef unsigned short us8 __attribute__((ext_vector_type(8)));

__device__ __forceinline__ unsigned short f2bf(float f) {
  return __builtin_bit_cast(unsigned short, (__bf16)f);
}
__device__ __forceinline__ float bf2f(unsigned short u) {
  return (float)__builtin_bit_cast(__bf16, u);
}

// async global->LDS, 16B per lane; LDS dest is wave-uniform base + lane*16
__device__ __forceinline__ void async_lds16(const unsigned short* g, unsigned short* l) {
  __builtin_amdgcn_global_load_lds(
      (__attribute__((address_space(1))) void*)(size_t)(const void*)g,
      (__attribute__((address_space(3))) void*)l,
      16, 0, 0);
}

// ---------------- f32 -> bf16 cast (4 elems/thread) ----------------
__global__ __launch_bounds__(256) void cvt_f32_bf16(
    const float* __restrict__ src, unsigned short* __restrict__ dst, int n4) {
  int t = blockIdx.x * 256 + threadIdx.x;
  if (t >= n4) return;
  float4 v = reinterpret_cast<const float4*>(src)[t];
  ushort4 o;
  o.x = f2bf(v.x); o.y = f2bf(v.y); o.z = f2bf(v.z); o.w = f2bf(v.w);
  reinterpret_cast<ushort4*>(dst)[t] = o;
}

// ---------------- 256x256 pipelined bf16 GEMM, C = A * B^T ----------------
// LDS: 2 bufs x {A,B} x {K-half}, each region 256 rows x 32 elems (16 KB),
// 128 KiB total. Row r granule g (16B, 4/row) at slot g ^ ((r>>1)&3):
// 16-row x 4-slot fragment reads cover every granule of a 1KB block once
// per wave -> conflict-free (measured 0).
template <bool OUT_BF16>
__global__ __launch_bounds__(512, 2) void gemm256(
    const unsigned short* __restrict__ A, const unsigned short* __restrict__ Bm,
    void* __restrict__ Cv, int K, int lda, int ldb, int ldc) {
  __shared__ __align__(16) unsigned short lds[65536];  // 128 KiB

  const int tid  = threadIdx.x;
  const int lane = tid & 63;
  const int wave = tid >> 6;

  // T1: XCD-aware bijective block swizzle (launcher guarantees nwg % 8 == 0)
  const int nbx  = gridDim.x;
  const int nwg  = nbx * gridDim.y;
  const int orig = blockIdx.y * nbx + blockIdx.x;
  const int swz  = (orig & 7) * (nwg >> 3) + (orig >> 3);
  const int bm   = (swz / nbx) * 256;
  const int bn   = (swz % nbx) * 256;

  const int wm  = wave >> 2;        // 0..1: 128-row block
  const int wn  = wave & 3;         // 0..3: 64-col block
  const int l15 = lane & 15;
  const int kq  = lane >> 4;        // k-granule: frag k = kq*8..+8
  const int swzr = kq ^ ((l15 >> 1) & 3);            // swizzled slot
  const int aoff = (wm * 128 + l15) * 32 + swzr * 8; // elems within A region
  const int boff = (wn * 64  + l15) * 32 + swzr * 8; // elems within B region

  // staging geometry: granule idx = j*512 + wave*64 + lane
  //   row = granule>>2, slot = granule&3; global granule = slot ^ ((row>>1)&3)
  const int srow = wave * 16 + (lane >> 2);
  const int sg   = (lane & 3) ^ ((lane >> 3) & 3);   // pre-swizzled global granule
  const unsigned short* gAr = A  + (size_t)(bm + srow) * lda + sg * 8;
  const unsigned short* gBr = Bm + (size_t)(bn + srow) * ldb + sg * 8;

  auto STAGE = [&](int t, int mat, int kh) {
    unsigned short* ldst = lds + ((((t & 1) * 2 + mat) * 2 + kh) << 13) + wave * 512;
    const unsigned short* g = (mat ? gBr : gAr) + t * 64 + kh * 32;
    const size_t ldx = mat ? (size_t)ldb : (size_t)lda;
    async_lds16(g, ldst);                     // rows 0..127 of region
    async_lds16(g + 128 * ldx, ldst + 4096);  // rows 128..255
  };

  f32x4 acc[8][4];
#pragma unroll
  for (int i = 0; i < 8; ++i)
#pragma unroll
    for (int j = 0; j < 4; ++j) acc[i][j] = (f32x4){0.f, 0.f, 0.f, 0.f};

  const int NT = K >> 6;

  // prologue: tile0 full + tile1 {B-k0, A-k0, B-k1}; newest 3 stay in flight
  STAGE(0, 0, 0); STAGE(0, 1, 0); STAGE(0, 0, 1); STAGE(0, 1, 1);
  if (NT > 1) {
    STAGE(1, 1, 0); STAGE(1, 0, 0); STAGE(1, 1, 1);
    asm volatile("s_waitcnt vmcnt(6)" ::: "memory");
  } else {
    asm volatile("s_waitcnt vmcnt(0)" ::: "memory");
  }
  asm volatile("s_barrier" ::: "memory");

  for (int t = 0; t < NT; ++t) {
    const unsigned short* Ak0 = lds + (t & 1) * 32768;
    const unsigned short* Ak1 = Ak0 + 8192;
    const unsigned short* Bk0 = Ak0 + 16384;
    const unsigned short* Bk1 = Ak0 + 24576;

    bf16x8 aE[4], aO[4], bE[4], bO[4];

    // tile-start reads: P0 operands (serial drain, buffer valid per boundary)
#pragma unroll
    for (int i = 0; i < 4; ++i)
      aE[i] = *reinterpret_cast<const bf16x8*>(Ak0 + aoff + i * 512);
#pragma unroll
    for (int j = 0; j < 4; ++j)
      bE[j] = *reinterpret_cast<const bf16x8*>(Bk0 + boff + j * 512);

    // ---- P0: rows 0..63, K 0..31; prefetch P1's A; MFMA(aE,bE) ----
    if (t + 1 < NT) STAGE(t + 1, 0, 1);
#pragma unroll
    for (int i = 0; i < 4; ++i)
      aO[i] = *reinterpret_cast<const bf16x8*>(Ak0 + aoff + 2048 + i * 512);
    __builtin_amdgcn_s_setprio(1);
#pragma unroll
    for (int i = 0; i < 4; ++i)
#pragma unroll
      for (int j = 0; j < 4; ++j)
        acc[i][j] = __builtin_amdgcn_mfma_f32_16x16x32_bf16(aE[i], bE[j], acc[i][j], 0, 0, 0);
    __builtin_amdgcn_s_setprio(0);
    asm volatile("s_barrier" ::: "memory");   // B.k0 readers drained

    // ---- P1: rows 64..127, K 0..31; prefetch P2's A; MFMA(aO,bE) ----
    if (t + 2 < NT) STAGE(t + 2, 1, 0);
#pragma unroll
    for (int i = 0; i < 4; ++i)
      aE[i] = *reinterpret_cast<const bf16x8*>(Ak1 + aoff + i * 512);
    __builtin_amdgcn_s_setprio(1);
#pragma unroll
    for (int i = 0; i < 4; ++i)
#pragma unroll
      for (int j = 0; j < 4; ++j)
        acc[4 + i][j] = __builtin_amdgcn_mfma_f32_16x16x32_bf16(aO[i], bE[j], acc[4 + i][j], 0, 0, 0);
    __builtin_amdgcn_s_setprio(0);
    asm volatile("s_barrier" ::: "memory");   // A.k0 readers drained

    // ---- P2: rows 0..63, K 32..63; read B.k1 + prefetch P3's A; MFMA(aE,bO) ----
    if (t + 2 < NT) STAGE(t + 2, 0, 0);
#pragma unroll
    for (int j = 0; j < 4; ++j)
      bO[j] = *reinterpret_cast<const bf16x8*>(Bk1 + boff + j * 512);
#pragma unroll
    for (int i = 0; i < 4; ++i)
      aO[i] = *reinterpret_cast<const bf16x8*>(Ak1 + aoff + 2048 + i * 512);
    __builtin_amdgcn_s_setprio(1);
#pragma unroll
    for (int i = 0; i < 4; ++i)
#pragma unroll
      for (int j = 0; j < 4; ++j)
        acc[i][j] = __builtin_amdgcn_mfma_f32_16x16x32_bf16(aE[i], bO[j], acc[i][j], 0, 0, 0);
    __builtin_amdgcn_s_setprio(0);
    asm volatile("s_barrier" ::: "memory");   // B.k1 readers drained

    // ---- P3: rows 64..127, K 32..63; MFMA(aO,bO) ----
    if (t + 2 < NT) STAGE(t + 2, 1, 1);
    __builtin_amdgcn_s_setprio(1);
#pragma unroll
    for (int i = 0; i < 4; ++i)
#pragma unroll
      for (int j = 0; j < 4; ++j)
        acc[4 + i][j] = __builtin_amdgcn_mfma_f32_16x16x32_bf16(aO[i], bO[j], acc[4 + i][j], 0, 0, 0);
    __builtin_amdgcn_s_setprio(0);
    // tile boundary: counted drain (3 half-tiles in flight), then barrier
    if (t == NT - 2)      asm volatile("s_waitcnt vmcnt(0)" ::: "memory");
    else if (t < NT - 2)  asm volatile("s_waitcnt vmcnt(6)" ::: "memory");
    asm volatile("s_barrier" ::: "memory");
  }

  // epilogue: C/D layout col=lane&15, row=(lane>>4)*4+reg
#pragma unroll
  for (int mi = 0; mi < 8; ++mi) {
#pragma unroll
    for (int j = 0; j < 4; ++j) {
      const int col = bn + wn * 64 + j * 16 + l15;
#pragma unroll
      for (int r = 0; r < 4; ++r) {
        const int row = bm + wm * 128 + mi * 16 + kq * 4 + r;
        if (OUT_BF16)
          ((unsigned short*)Cv)[(size_t)row * ldc + col] = f2bf(acc[mi][j][r]);
        else
          ((float*)Cv)[(size_t)row * ldc + col] = acc[mi][j][r];
      }
    }
  }
}

// ---------------- chunked decay scan + sigmoid gate (in-place on x half) ----
__global__ __launch_bounds__(256) void scan_gate(
    unsigned short* __restrict__ xz, const float* __restrict__ A_log) {
  const int tid = blockIdx.x * 256 + threadIdx.x;   // 458752 total
  const int i8 = tid % 896;
  const int rb = tid / 896;
  const int r = rb & 255;
  const int b = rb >> 8;
  const int i = i8 * 8;
  const float Ah = __expf(-fabsf(A_log[i >> 6]));   // head = i/64

  float st[8];
#pragma unroll
  for (int j = 0; j < 8; ++j) st[j] = 0.f;

  const size_t base = ((size_t)b * 4096 + r) * 14336 + i;
#pragma unroll
  for (int c = 0; c < 16; ++c) {
    const size_t off = base + (size_t)c * (256 * 14336);
    us8 xr = *reinterpret_cast<const us8*>(xz + off);
    us8 zr = *reinterpret_cast<const us8*>(xz + off + 7168);
    us8 yo;
#pragma unroll
    for (int j = 0; j < 8; ++j) {
      st[j] = st[j] * Ah + 0.1f * bf2f(xr[j]);
      const float zv = bf2f(zr[j]);
      const float sg = 1.f / (1.f + __expf(-zv));
      yo[j] = f2bf(st[j] * sg);
    }
    *reinterpret_cast<us8*>(xz + off) = yo;  // y overwrites x slot
  }
}

extern "C" void kernel_launch(void* const* d_in, const int* in_sizes, int n_in,
                              void* d_out, int out_size, void* d_ws, size_t ws_size,
                              hipStream_t stream) {
  const float* hidden = (const float*)d_in[0];   // [2,4096,3584]
  const float* W_in   = (const float*)d_in[1];   // [14336,3584]
  const float* W_out  = (const float*)d_in[2];   // [3584,7168]
  const float* A_log  = (const float*)d_in[3];   // [112]

  // workspace layout (bf16 elems): hid | win | wout | xz   = 447.7 MB total
  unsigned short* hid_bf  = (unsigned short*)d_ws;
  unsigned short* win_bf  = hid_bf  + 29360128ull;   // 2*4096*3584
  unsigned short* wout_bf = win_bf  + 51380224ull;   // 14336*3584
  unsigned short* xz      = wout_bf + 25690112ull;   // 3584*7168; xz = 8192*14336

  cvt_f32_bf16<<<29360128 / 4 / 256, 256, 0, stream>>>(hidden, hid_bf, 29360128 / 4);
  cvt_f32_bf16<<<51380224 / 4 / 256, 256, 0, stream>>>(W_in, win_bf, 51380224 / 4);
  cvt_f32_bf16<<<25690112 / 4 / 256, 256, 0, stream>>>(W_out, wout_bf, 25690112 / 4);

  // GEMM1: xz = hidden * W_in^T   (M=8192, N=14336, K=3584) -> 56x32 = 1792 wgs
  gemm256<true><<<dim3(14336 / 256, 8192 / 256), 512, 0, stream>>>(
      hid_bf, win_bf, xz, 3584, 3584, 3584, 14336);

  scan_gate<<<1792, 256, 0, stream>>>(xz, A_log);

  // GEMM2: out = y * W_out^T   (M=8192, N=3584, K=7168, A lda=14336) -> 14x32 = 448 wgs
  gemm256<false><<<dim3(3584 / 256, 8192 / 256), 512, 0, stream>>>(
      xz, wout_bf, d_out, 7168, 14336, 7168, 3584);
}